// Round 4
// baseline (444.320 us; speedup 1.0000x reference)
//
#include <hip/hip_runtime.h>

// ---------------- problem constants ----------------
// x:[N,128] W1:[128,128] b1:[128] W2:[128,64] b2:[64] edge_index:[2,E]
// out:[N,64] fp32. Intermediates bf16; GEMMs use bf16 MFMA (fp32 accum).
// GEMM is LDS-free: W pre-swizzled to bf16 frag tables (L1-resident);
// A frags loaded straight from global. CSR built with 3-pass global atomics.

// ---------------- workspace layout (bytes) ----------------
static constexpr size_t OFF_FLAG = 0;         // u32[1]
static constexpr size_t OFF_DEG  = 256;       // u32[N]  (becomes scatter cursor)
static constexpr size_t OFF_ROW  = 458752;    // u32[N+1]
static constexpr size_t OFF_BSUM = 917504;    // u32[1024]
static constexpr size_t OFF_DINV = 962560;    // f32[N]
static constexpr size_t OFF_CSR  = 1376256;   // i32[E]            (6.4 MB)
static constexpr size_t OFF_HS1  = 8388608;   // bf16[N*128] 25.6 MB
static constexpr size_t OFF_OUT1 = 35651584;  // bf16[N*128] 25.6 MB
static constexpr size_t OFF_HS2  = 62914560;  // bf16[N*64]  12.8 MB (ends 75714560)
static constexpr size_t OFF_W1S  = 75714560;  // bf16[128*128] swizzled (32 KB)
static constexpr size_t OFF_W2S  = 75747328;  // bf16[128*64]  swizzled (16 KB)

// ---------------- bf16 helpers ----------------
__device__ __forceinline__ unsigned short f2bf(float f) {  // RNE
    unsigned u = __float_as_uint(f);
    u += 0x7fffu + ((u >> 16) & 1u);
    return (unsigned short)(u >> 16);
}

typedef __attribute__((ext_vector_type(8))) short bf16x8;
typedef __attribute__((ext_vector_type(4))) float f32x4;

// ---------------- edge dtype access ----------------
__device__ __forceinline__ int edge_dst(const unsigned* w, unsigned flag,
                                        int e, int E) {
    return flag ? (int)w[E + e] : (int)w[2 * E + 2 * e];
}
__device__ __forceinline__ int edge_src(const unsigned* w, unsigned flag,
                                        int e, int E) {
    return flag ? (int)w[e] : (int)w[2 * e];
}

// ---------------- W pre-swizzle: fp32 [128][BN] -> bf16 frag table ---------
// frag layout (m89-verified, same formula as the old sB staging):
// element (k,n) -> ((((n>>4)*4 + (k>>5))*16 + (n&15))*4 + ((k>>3)&3))*8 + (k&7)
__global__ __launch_bounds__(256) void wprep_kernel(
    const float* __restrict__ W1, const float* __restrict__ W2,
    unsigned short* __restrict__ O1, unsigned short* __restrict__ O2) {
    const float* W = blockIdx.x ? W2 : W1;
    unsigned short* O = blockIdx.x ? O2 : O1;
    const int BN = blockIdx.x ? 64 : 128;
    const int total = 128 * BN / 4;
    for (int g = threadIdx.x; g < total; g += 256) {
        int n = g % BN, k0 = (g / BN) * 4;
        ushort4 u;
        u.x = f2bf(W[(size_t)(k0 + 0) * BN + n]);
        u.y = f2bf(W[(size_t)(k0 + 1) * BN + n]);
        u.z = f2bf(W[(size_t)(k0 + 2) * BN + n]);
        u.w = f2bf(W[(size_t)(k0 + 3) * BN + n]);
        int off = ((((n >> 4) * 4 + (k0 >> 5)) * 16 + (n & 15)) * 4 +
                   ((k0 >> 3) & 3)) * 8 + (k0 & 4);
        *(ushort4*)(O + off) = u;
    }
}

// ---------------- CSR build: deg zero + dtype detect ----------------
__global__ __launch_bounds__(256) void init_deg_detect(
    const unsigned* __restrict__ w, unsigned* __restrict__ flag,
    unsigned* __restrict__ deg, int N) {
    int i = blockIdx.x * 256 + threadIdx.x;
    if (i < N) deg[i] = 0u;
    if (i < 4096 && w[2 * i + 1] != 0u) atomicOr(flag, 1u);
}

// ---------------- deg count via global atomics ----------------
__global__ __launch_bounds__(256) void deg_kernel(
    const unsigned* __restrict__ w, const unsigned* __restrict__ flag,
    unsigned* __restrict__ deg, int E) {
    int e = blockIdx.x * 256 + threadIdx.x;
    if (e >= E) return;
    const unsigned f = *flag;
    atomicAdd(&deg[edge_dst(w, f, e, E)], 1u);
}

// ---------------- scans over deg -> row; dinv; cursor ----------------
__global__ __launch_bounds__(1024) void scan1_kernel(
    const unsigned* __restrict__ deg, unsigned* __restrict__ row,
    unsigned* __restrict__ bsum, int N) {
    __shared__ unsigned sh[1024];
    int gid = blockIdx.x * 1024 + threadIdx.x;
    int t = threadIdx.x;
    unsigned v = (gid < N) ? deg[gid] : 0u;
    sh[t] = v;
    __syncthreads();
#pragma unroll
    for (int off = 1; off < 1024; off <<= 1) {
        unsigned add = (t >= off) ? sh[t - off] : 0u;
        __syncthreads();
        sh[t] += add;
        __syncthreads();
    }
    if (gid < N) row[gid + 1] = sh[t];
    if (t == 1023) bsum[blockIdx.x] = sh[1023];
}

__global__ __launch_bounds__(1024) void scan2_kernel(unsigned* __restrict__ bsum,
                                                     int NB) {
    __shared__ unsigned sh[1024];
    const int t = threadIdx.x;
    unsigned v = (t < NB) ? bsum[t] : 0u;
    sh[t] = v;
    __syncthreads();
#pragma unroll
    for (int off = 1; off < 1024; off <<= 1) {
        unsigned a = (t >= off) ? sh[t - off] : 0u;
        __syncthreads();
        sh[t] += a;
        __syncthreads();
    }
    if (t < NB) bsum[t] = sh[t] - v;
}

// row finalize + dinv + write scatter cursor (row[i]) into deg[]
__global__ __launch_bounds__(256) void scan3_kernel(
    unsigned* __restrict__ row, const unsigned* __restrict__ bsum,
    unsigned* __restrict__ deg, float* __restrict__ dinv, int N) {
    int gid = blockIdx.x * 256 + threadIdx.x;
    if (gid >= N) return;
    unsigned r1 = row[gid + 1] + bsum[gid >> 10];
    row[gid + 1] = r1;
    if (gid == 0) row[0] = 0u;
    unsigned d = deg[gid];
    dinv[gid] = rsqrtf((float)d + 1.0f);
    deg[gid] = r1 - d;           // exclusive offset = final row[gid]
}

// ---------------- scatter: csr[cursor[dst]++] = src ----------------
__global__ __launch_bounds__(256) void scatter_kernel(
    const unsigned* __restrict__ w, const unsigned* __restrict__ flag,
    unsigned* __restrict__ cur, int* __restrict__ csr, int E) {
    int e = blockIdx.x * 256 + threadIdx.x;
    if (e >= E) return;
    const unsigned f = *flag;
    int d = edge_dst(w, f, e, E);
    int s = edge_src(w, f, e, E);
    unsigned pos = atomicAdd(&cur[d], 1u);
    csr[pos] = s;
}

// ---------------- LDS-free MFMA GEMM: out_bf16 = (A @ B) * dinv[row] -------
// 128xBN rows per block, K=128, 16x16x32 bf16 MFMA, 4 waves x 2 m-tiles.
// A frags direct from global (lane m=lane&15,q=lane>>4 reads
// A[mt*16+m][ks*32+q*8 .. +7]); B frags from the pre-swizzled table
// (1 KB contiguous per wave-load, L1-resident).
template <int BN, bool ABF16>
__global__ __launch_bounds__(256) void gemm_mfma(
    const void* __restrict__ Av, const unsigned short* __restrict__ Bs,
    const float* __restrict__ dinv, unsigned short* __restrict__ out, int M) {
    constexpr int NT = BN / 16;
    const int t = threadIdx.x;
    const int row0 = blockIdx.x * 128;
    const int w = t >> 6, lane = t & 63;
    const int m = lane & 15, q = lane >> 4;
    const int fb = (m * 4 + q) * 8;

    const int r0 = row0 + (2 * w) * 16 + m;       // m-tile 2w
    const int r1 = r0 + 16;                        // m-tile 2w+1

    f32x4 acc[2][NT];
#pragma unroll
    for (int lt = 0; lt < 2; lt++)
#pragma unroll
        for (int nt = 0; nt < NT; nt++) acc[lt][nt] = (f32x4){0.f, 0.f, 0.f, 0.f};

#pragma unroll
    for (int ks = 0; ks < 4; ks++) {
        const int k0 = ks * 32 + q * 8;
        bf16x8 a0 = (bf16x8){0, 0, 0, 0, 0, 0, 0, 0};
        bf16x8 a1 = (bf16x8){0, 0, 0, 0, 0, 0, 0, 0};
        if (ABF16) {
            const unsigned short* A = (const unsigned short*)Av;
            if (r0 < M) a0 = *(const bf16x8*)(A + (size_t)r0 * 128 + k0);
            if (r1 < M) a1 = *(const bf16x8*)(A + (size_t)r1 * 128 + k0);
        } else {
            const float* A = (const float*)Av;
            if (r0 < M) {
                const float* p = A + (size_t)r0 * 128 + k0;
                f32x4 lo = *(const f32x4*)p, hi = *(const f32x4*)(p + 4);
                a0[0] = (short)f2bf(lo[0]); a0[1] = (short)f2bf(lo[1]);
                a0[2] = (short)f2bf(lo[2]); a0[3] = (short)f2bf(lo[3]);
                a0[4] = (short)f2bf(hi[0]); a0[5] = (short)f2bf(hi[1]);
                a0[6] = (short)f2bf(hi[2]); a0[7] = (short)f2bf(hi[3]);
            }
            if (r1 < M) {
                const float* p = A + (size_t)r1 * 128 + k0;
                f32x4 lo = *(const f32x4*)p, hi = *(const f32x4*)(p + 4);
                a1[0] = (short)f2bf(lo[0]); a1[1] = (short)f2bf(lo[1]);
                a1[2] = (short)f2bf(lo[2]); a1[3] = (short)f2bf(lo[3]);
                a1[4] = (short)f2bf(hi[0]); a1[5] = (short)f2bf(hi[1]);
                a1[6] = (short)f2bf(hi[2]); a1[7] = (short)f2bf(hi[3]);
            }
        }
#pragma unroll
        for (int nt = 0; nt < NT; nt++) {
            bf16x8 b = *(const bf16x8*)(Bs + (nt * 4 + ks) * 512 + fb);
            acc[0][nt] = __builtin_amdgcn_mfma_f32_16x16x32_bf16(a0, b, acc[0][nt], 0, 0, 0);
            acc[1][nt] = __builtin_amdgcn_mfma_f32_16x16x32_bf16(a1, b, acc[1][nt], 0, 0, 0);
        }
    }

    // ---- epilogue: scale by dinv, store bf16 ----
#pragma unroll
    for (int lt = 0; lt < 2; lt++) {
#pragma unroll
        for (int r = 0; r < 4; r++) {
            int row = row0 + w * 32 + lt * 16 + q * 4 + r;
            if (row < M) {
                float s = dinv[row];
#pragma unroll
                for (int nt = 0; nt < NT; nt++)
                    out[(size_t)row * BN + nt * 16 + m] = f2bf(acc[lt][nt][r] * s);
            }
        }
    }
}

// ---------------- gather aggregation + fused epilogue (round-0 proven) -----
// out[i] = maybe_relu( dinv[i] * ( hs[i] + sum_{e in row i} hs[csr[e]] ) + b )
// Lane owns 8 channels (uint4 = 16 B of bf16). LPN = C/8 lanes per node.
template <int C, bool RELU, bool OUTBF>
__global__ __launch_bounds__(256) void agg_kernel(
    const int* __restrict__ csr, const unsigned* __restrict__ row,
    const unsigned short* __restrict__ hsb, const float* __restrict__ dinv,
    const float* __restrict__ bias, void* __restrict__ outv, int N) {
    constexpr int LPN = C / 8;  // lanes per node (16 or 8)
    const int tid = blockIdx.x * 256 + threadIdx.x;
    const int i = tid / LPN;
    const int l = tid % LPN;
    if (i >= N) return;

    const int co = 8 * l;
    float s0 = 0.f, s1 = 0.f, s2 = 0.f, s3 = 0.f,
          s4 = 0.f, s5 = 0.f, s6 = 0.f, s7 = 0.f;
    {
        uint4 u = *(const uint4*)(hsb + (size_t)i * C + co);   // self
        s0 += __uint_as_float(u.x << 16); s1 += __uint_as_float(u.x & 0xffff0000u);
        s2 += __uint_as_float(u.y << 16); s3 += __uint_as_float(u.y & 0xffff0000u);
        s4 += __uint_as_float(u.z << 16); s5 += __uint_as_float(u.z & 0xffff0000u);
        s6 += __uint_as_float(u.w << 16); s7 += __uint_as_float(u.w & 0xffff0000u);
    }

    const int rs = (int)row[i], re = (int)row[i + 1];
    for (int e0 = rs; e0 < re; e0 += LPN) {
        int idx = (e0 + l < re) ? csr[e0 + l] : 0;
        const int cnt = min(LPN, re - e0);
#pragma unroll 4
        for (int j = 0; j < cnt; j++) {
            int s = __shfl(idx, j, LPN);
            uint4 u = *(const uint4*)(hsb + (size_t)s * C + co);
            s0 += __uint_as_float(u.x << 16); s1 += __uint_as_float(u.x & 0xffff0000u);
            s2 += __uint_as_float(u.y << 16); s3 += __uint_as_float(u.y & 0xffff0000u);
            s4 += __uint_as_float(u.z << 16); s5 += __uint_as_float(u.z & 0xffff0000u);
            s6 += __uint_as_float(u.w << 16); s7 += __uint_as_float(u.w & 0xffff0000u);
        }
    }

    const float sc = dinv[i];
    const float4 ba = *(const float4*)(bias + co);
    const float4 bb = *(const float4*)(bias + co + 4);
    float o0 = s0 * sc + ba.x, o1 = s1 * sc + ba.y;
    float o2 = s2 * sc + ba.z, o3 = s3 * sc + ba.w;
    float o4 = s4 * sc + bb.x, o5 = s5 * sc + bb.y;
    float o6 = s6 * sc + bb.z, o7 = s7 * sc + bb.w;
    if (RELU) {
        o0 = fmaxf(o0, 0.f); o1 = fmaxf(o1, 0.f); o2 = fmaxf(o2, 0.f);
        o3 = fmaxf(o3, 0.f); o4 = fmaxf(o4, 0.f); o5 = fmaxf(o5, 0.f);
        o6 = fmaxf(o6, 0.f); o7 = fmaxf(o7, 0.f);
    }
    if (OUTBF) {
        uint4 u;
        u.x = (unsigned)f2bf(o0) | ((unsigned)f2bf(o1) << 16);
        u.y = (unsigned)f2bf(o2) | ((unsigned)f2bf(o3) << 16);
        u.z = (unsigned)f2bf(o4) | ((unsigned)f2bf(o5) << 16);
        u.w = (unsigned)f2bf(o6) | ((unsigned)f2bf(o7) << 16);
        *(uint4*)((unsigned short*)outv + (size_t)i * C + co) = u;
    } else {
        float4 a = make_float4(o0, o1, o2, o3);
        float4 b = make_float4(o4, o5, o6, o7);
        *(float4*)((float*)outv + (size_t)i * C + co) = a;
        *(float4*)((float*)outv + (size_t)i * C + co + 4) = b;
    }
}

// ---------------- launch ----------------
extern "C" void kernel_launch(void* const* d_in, const int* in_sizes, int n_in,
                              void* d_out, int out_size, void* d_ws,
                              size_t ws_size, hipStream_t stream) {
    const float* x  = (const float*)d_in[0];
    const float* W1 = (const float*)d_in[1];
    const float* b1 = (const float*)d_in[2];
    const float* W2 = (const float*)d_in[3];
    const float* b2 = (const float*)d_in[4];
    const unsigned* ew = (const unsigned*)d_in[5];
    const int E = in_sizes[5] / 2;        // 1,600,000
    const int N = in_sizes[0] / 128;      // 100,000
    const int NB = (N + 1023) >> 10;

    char* ws = (char*)d_ws;
    unsigned* flag = (unsigned*)(ws + OFF_FLAG);
    unsigned* deg  = (unsigned*)(ws + OFF_DEG);
    unsigned* row  = (unsigned*)(ws + OFF_ROW);
    unsigned* bsum = (unsigned*)(ws + OFF_BSUM);
    float* dinv    = (float*)(ws + OFF_DINV);
    int* csr       = (int*)(ws + OFF_CSR);
    unsigned short* hs1  = (unsigned short*)(ws + OFF_HS1);
    unsigned short* out1 = (unsigned short*)(ws + OFF_OUT1);
    unsigned short* hs2  = (unsigned short*)(ws + OFF_HS2);
    unsigned short* w1s  = (unsigned short*)(ws + OFF_W1S);
    unsigned short* w2s  = (unsigned short*)(ws + OFF_W2S);

    hipMemsetAsync(flag, 0, 4, stream);

    // ---- W pre-swizzle (independent of everything else) ----
    wprep_kernel<<<2, 256, 0, stream>>>(W1, W2, w1s, w2s);

    // ---- CSR build (3-pass atomic) ----
    init_deg_detect<<<(N + 255) / 256, 256, 0, stream>>>(ew, flag, deg, N);
    deg_kernel<<<(E + 255) / 256, 256, 0, stream>>>(ew, flag, deg, E);
    scan1_kernel<<<NB, 1024, 0, stream>>>(deg, row, bsum, N);
    scan2_kernel<<<1, 1024, 0, stream>>>(bsum, NB);
    scan3_kernel<<<(N + 255) / 256, 256, 0, stream>>>(row, bsum, deg, dinv, N);
    scatter_kernel<<<(E + 255) / 256, 256, 0, stream>>>(ew, flag, deg, csr, E);

    // ---- layer 1 (C=128) ----
    gemm_mfma<128, false><<<(N + 127) / 128, 256, 0, stream>>>(x, w1s, dinv, hs1, N);
    agg_kernel<128, true, true><<<(N * 16 + 255) / 256, 256, 0, stream>>>(
        csr, row, hs1, dinv, b1, out1, N);

    // ---- layer 2 (C=64) ----
    gemm_mfma<64, true><<<(N + 127) / 128, 256, 0, stream>>>(out1, w2s, dinv, hs2, N);
    agg_kernel<64, false, false><<<(N * 8 + 255) / 256, 256, 0, stream>>>(
        csr, row, hs2, dinv, b2, d_out, N);
}

// Round 5
// 305.665 us; speedup vs baseline: 1.4536x; 1.4536x over previous
//
#include <hip/hip_runtime.h>

// ---------------- problem constants ----------------
// x:[N,128] W1:[128,128] b1:[128] W2:[128,64] b2:[64] edge_index:[2,E]
// out:[N,64] fp32. Intermediates bf16; GEMMs use bf16 MFMA (fp32 accum).
// CSR build: round-0 bucketed-partition chain (random writes stay line-local;
// round-4 measured: naive atomic scatter = 105 MB write-allocate, 130 us).
// GEMM: LDS-free; W pre-swizzled into bf16 frag tables (L1-resident), A frags
// loaded directly from global. No barriers, no LDS occupancy cap.

static constexpr int BSHIFT = 7;          // 128 node ids per coarse bucket
static constexpr int BWIDTH = 1 << BSHIFT;
static constexpr int MAXBUCK = 2048;      // supports N <= 262144 (pack needs N < 2^20)
static constexpr int NPART = 256;         // partition/hist grid size

// ---------------- workspace layout (bytes) ----------------
static constexpr size_t OFF_FLAG = 0;         // u32[1]
static constexpr size_t OFF_DEG  = 256;       // u32[N]
static constexpr size_t OFF_ROW  = 458752;    // u32[N+1]
static constexpr size_t OFF_BSUM = 917504;    // u32[1024]
static constexpr size_t OFF_CCNT = 925696;    // u32[MAXBUCK+1]
static constexpr size_t OFF_COFF = 937984;    // u32[MAXBUCK+1]
static constexpr size_t OFF_DINV = 962560;    // f32[N]
static constexpr size_t OFF_CSR  = 1376256;   // i32[E]            (6.4 MB)
static constexpr size_t OFF_HS1  = 8388608;   // bf16[N*128] 25.6 MB; aliases part u32[E]
static constexpr size_t OFF_OUT1 = 35651584;  // bf16[N*128] 25.6 MB
static constexpr size_t OFF_HS2  = 62914560;  // bf16[N*64]  12.8 MB (ends 75714560)
static constexpr size_t OFF_H2   = 75714560;  // u32[MAXBUCK*NPART] (2 MB region)
static constexpr size_t OFF_W1S  = 77811712;  // bf16[128*128] swizzled (32 KB)
static constexpr size_t OFF_W2S  = 77844480;  // bf16[128*64]  swizzled (16 KB)

// ---------------- bf16 helpers ----------------
__device__ __forceinline__ unsigned short f2bf(float f) {  // RNE
    unsigned u = __float_as_uint(f);
    u += 0x7fffu + ((u >> 16) & 1u);
    return (unsigned short)(u >> 16);
}

typedef __attribute__((ext_vector_type(8))) short bf16x8;
typedef __attribute__((ext_vector_type(4))) float f32x4;

// ---------------- edge dtype detection (+ ccnt zeroing, fused) -----------
__global__ void detect_kernel(const unsigned* __restrict__ w,
                              unsigned* __restrict__ flag,
                              unsigned* __restrict__ ccnt, int nbuck) {
    int i = blockIdx.x * blockDim.x + threadIdx.x;   // 4096 threads
    if (i <= nbuck) ccnt[i] = 0;
    if (w[2 * i + 1] != 0u) atomicOr(flag, 1u);
}

__device__ __forceinline__ int edge_dst(const unsigned* w, unsigned flag,
                                        int e, int E) {
    return flag ? (int)w[E + e] : (int)w[2 * E + 2 * e];
}
__device__ __forceinline__ int edge_src(const unsigned* w, unsigned flag,
                                        int e, int E) {
    return flag ? (int)w[e] : (int)w[2 * e];
}

// ---------------- pass A: coarse histogram (stores per-block hist) ---------
__global__ __launch_bounds__(1024) void coarse_hist_kernel(
    const unsigned* __restrict__ w, const unsigned* __restrict__ flag,
    unsigned* __restrict__ ccnt, unsigned* __restrict__ h2, int E, int nbuck) {
    __shared__ unsigned hist[MAXBUCK];
    for (int i = threadIdx.x; i < nbuck; i += 1024) hist[i] = 0;
    __syncthreads();
    const unsigned f = *flag;
    const int per = (E + gridDim.x - 1) / gridDim.x;
    const int e0 = blockIdx.x * per, e1 = min(E, e0 + per);
    for (int e = e0 + (int)threadIdx.x; e < e1; e += 1024)
        atomicAdd(&hist[edge_dst(w, f, e, E) >> BSHIFT], 1u);
    __syncthreads();
    for (int i = threadIdx.x; i < nbuck; i += 1024) {
        unsigned h = hist[i];
        h2[(size_t)i * NPART + blockIdx.x] = h;
        if (h) atomicAdd(&ccnt[i], h);
    }
}

// ---------------- coarse scan: coff = exclusive_scan(ccnt) ----------------
__global__ __launch_bounds__(1024) void coarse_scan_kernel(
    const unsigned* __restrict__ ccnt, unsigned* __restrict__ coff, int nbuck) {
    __shared__ unsigned sh[1024];
    const int t = threadIdx.x;
    unsigned run = 0;
    for (int b0 = 0; b0 < nbuck; b0 += 1024) {
        unsigned v = (b0 + t < nbuck) ? ccnt[b0 + t] : 0u;
        sh[t] = v;
        __syncthreads();
        for (int off = 1; off < 1024; off <<= 1) {
            unsigned a = (t >= off) ? sh[t - off] : 0u;
            __syncthreads();
            sh[t] += a;
            __syncthreads();
        }
        if (b0 + t < nbuck) coff[b0 + t] = run + sh[t] - v;
        run += sh[1023];
        __syncthreads();
    }
    if (t == 0) coff[nbuck] = run;   // == E
}

// ---------------- off2d: h2[b][blk] -> per-block write cursor --------------
__global__ __launch_bounds__(NPART) void off2d_kernel(
    unsigned* __restrict__ h2, const unsigned* __restrict__ coff) {
    __shared__ unsigned sh[NPART];
    const int b = blockIdx.x, t = threadIdx.x;
    unsigned v = h2[(size_t)b * NPART + t];
    sh[t] = v;
    __syncthreads();
#pragma unroll
    for (int off = 1; off < NPART; off <<= 1) {
        unsigned a = (t >= off) ? sh[t - off] : 0u;
        __syncthreads();
        sh[t] += a;
        __syncthreads();
    }
    h2[(size_t)b * NPART + t] = coff[b] + sh[t] - v;   // exclusive + base
}

// ---------------- pass B: partition (packed 4 B entries) ----------------
// part entry = src | (dst&127)<<20  (valid: N < 2^20)
__global__ __launch_bounds__(1024) void partition_kernel(
    const unsigned* __restrict__ w, const unsigned* __restrict__ flag,
    const unsigned* __restrict__ h2, unsigned* __restrict__ part, int E,
    int nbuck) {
    __shared__ unsigned lcur[MAXBUCK];
    for (int i = threadIdx.x; i < nbuck; i += 1024)
        lcur[i] = h2[(size_t)i * NPART + blockIdx.x];
    __syncthreads();
    const unsigned f = *flag;
    const int per = (E + gridDim.x - 1) / gridDim.x;
    const int e0 = blockIdx.x * per, e1 = min(E, e0 + per);
    for (int e = e0 + (int)threadIdx.x; e < e1; e += 1024) {
        int d = edge_dst(w, f, e, E);
        int s = edge_src(w, f, e, E);
        unsigned pos = atomicAdd(&lcur[d >> BSHIFT], 1u);
        part[pos] = (unsigned)s | ((unsigned)(d & (BWIDTH - 1)) << 20);
    }
}

// ---------------- pass C: per-bucket deg + local scan + CSR write ----------
__global__ __launch_bounds__(256) void bucket_csr_kernel(
    const unsigned* __restrict__ part, const unsigned* __restrict__ coff,
    unsigned* __restrict__ deg, int* __restrict__ csr, int N) {
    __shared__ unsigned cnt[BWIDTH];
    __shared__ unsigned sc[BWIDTH];
    __shared__ unsigned cur[BWIDTH];
    const int b = blockIdx.x, base = b << BSHIFT, t = threadIdx.x;
    if (t < BWIDTH) cnt[t] = 0;
    __syncthreads();
    const int e0 = (int)coff[b], e1 = (int)coff[b + 1];
    for (int e = e0 + t; e < e1; e += 256)
        atomicAdd(&cnt[part[e] >> 20], 1u);
    __syncthreads();
    if (t < BWIDTH && base + t < N) deg[base + t] = cnt[t];
    if (t < BWIDTH) sc[t] = cnt[t];
    __syncthreads();
#pragma unroll
    for (int off = 1; off < BWIDTH; off <<= 1) {
        unsigned a = (t < BWIDTH && t >= off) ? sc[t - off] : 0u;
        __syncthreads();
        if (t < BWIDTH) sc[t] += a;
        __syncthreads();
    }
    if (t < BWIDTH) cur[t] = (unsigned)e0 + sc[t] - cnt[t];
    __syncthreads();
    for (int e = e0 + t; e < e1; e += 256) {
        unsigned pk = part[e];
        unsigned p = atomicAdd(&cur[pk >> 20], 1u);
        csr[p] = (int)(pk & 0xFFFFFu);
    }
}

// ---------------- scans over deg -> row; dinv ----------------
__global__ __launch_bounds__(1024) void scan1_kernel(
    const unsigned* __restrict__ deg, unsigned* __restrict__ row,
    unsigned* __restrict__ bsum, int N) {
    __shared__ unsigned sh[1024];
    int gid = blockIdx.x * 1024 + threadIdx.x;
    int t = threadIdx.x;
    unsigned v = (gid < N) ? deg[gid] : 0u;
    sh[t] = v;
    __syncthreads();
#pragma unroll
    for (int off = 1; off < 1024; off <<= 1) {
        unsigned add = (t >= off) ? sh[t - off] : 0u;
        __syncthreads();
        sh[t] += add;
        __syncthreads();
    }
    if (gid < N) row[gid + 1] = sh[t];
    if (t == 1023) bsum[blockIdx.x] = sh[1023];
}

__global__ __launch_bounds__(1024) void scan2_kernel(unsigned* __restrict__ bsum,
                                                     int NB) {
    __shared__ unsigned sh[1024];
    const int t = threadIdx.x;
    unsigned v = (t < NB) ? bsum[t] : 0u;
    sh[t] = v;
    __syncthreads();
#pragma unroll
    for (int off = 1; off < 1024; off <<= 1) {
        unsigned a = (t >= off) ? sh[t - off] : 0u;
        __syncthreads();
        sh[t] += a;
        __syncthreads();
    }
    if (t < NB) bsum[t] = sh[t] - v;
}

__global__ void scan3_kernel(unsigned* __restrict__ row,
                             const unsigned* __restrict__ bsum,
                             const unsigned* __restrict__ deg,
                             float* __restrict__ dinv, int N) {
    int gid = blockIdx.x * blockDim.x + threadIdx.x;
    if (gid >= N) return;
    row[gid + 1] += bsum[gid >> 10];
    if (gid == 0) row[0] = 0u;
    dinv[gid] = rsqrtf((float)deg[gid] + 1.0f);
}

// ---------------- W pre-swizzle: fp32 [128][BN] -> bf16 frag table ---------
// frag layout (m89-verified, same formula as the proven sB staging):
// element (k,n) -> ((((n>>4)*4 + (k>>5))*16 + (n&15))*4 + ((k>>3)&3))*8 + (k&7)
__global__ __launch_bounds__(256) void wprep_kernel(
    const float* __restrict__ W1, const float* __restrict__ W2,
    unsigned short* __restrict__ O1, unsigned short* __restrict__ O2) {
    const float* W = blockIdx.x ? W2 : W1;
    unsigned short* O = blockIdx.x ? O2 : O1;
    const int BN = blockIdx.x ? 64 : 128;
    const int total = 128 * BN / 4;
    for (int g = threadIdx.x; g < total; g += 256) {
        int n = g % BN, k0 = (g / BN) * 4;
        ushort4 u;
        u.x = f2bf(W[(size_t)(k0 + 0) * BN + n]);
        u.y = f2bf(W[(size_t)(k0 + 1) * BN + n]);
        u.z = f2bf(W[(size_t)(k0 + 2) * BN + n]);
        u.w = f2bf(W[(size_t)(k0 + 3) * BN + n]);
        int off = ((((n >> 4) * 4 + (k0 >> 5)) * 16 + (n & 15)) * 4 +
                   ((k0 >> 3) & 3)) * 8 + (k0 & 4);
        *(ushort4*)(O + off) = u;
    }
}

// ---------------- LDS-free MFMA GEMM: out_bf16 = (A @ B) * dinv[row] -------
// 128xBN rows per block, K=128, 16x16x32 bf16 MFMA, 4 waves x 2 m-tiles.
// A frags direct from global (lane m=lane&15,q=lane>>4 reads
// A[mt*16+m][ks*32+q*8 .. +7]); B frags from the pre-swizzled table
// (1 KB contiguous per wave-load, L1-resident).
template <int BN, bool ABF16>
__global__ __launch_bounds__(256) void gemm_mfma(
    const void* __restrict__ Av, const unsigned short* __restrict__ Bs,
    const float* __restrict__ dinv, unsigned short* __restrict__ out, int M) {
    constexpr int NT = BN / 16;
    const int t = threadIdx.x;
    const int row0 = blockIdx.x * 128;
    const int w = t >> 6, lane = t & 63;
    const int m = lane & 15, q = lane >> 4;
    const int fb = (m * 4 + q) * 8;

    const int r0 = row0 + (2 * w) * 16 + m;       // m-tile 2w
    const int r1 = r0 + 16;                        // m-tile 2w+1

    f32x4 acc[2][NT];
#pragma unroll
    for (int lt = 0; lt < 2; lt++)
#pragma unroll
        for (int nt = 0; nt < NT; nt++) acc[lt][nt] = (f32x4){0.f, 0.f, 0.f, 0.f};

#pragma unroll
    for (int ks = 0; ks < 4; ks++) {
        const int k0 = ks * 32 + q * 8;
        bf16x8 a0 = (bf16x8){0, 0, 0, 0, 0, 0, 0, 0};
        bf16x8 a1 = (bf16x8){0, 0, 0, 0, 0, 0, 0, 0};
        if (ABF16) {
            const unsigned short* A = (const unsigned short*)Av;
            if (r0 < M) a0 = *(const bf16x8*)(A + (size_t)r0 * 128 + k0);
            if (r1 < M) a1 = *(const bf16x8*)(A + (size_t)r1 * 128 + k0);
        } else {
            const float* A = (const float*)Av;
            if (r0 < M) {
                const float* p = A + (size_t)r0 * 128 + k0;
                f32x4 lo = *(const f32x4*)p, hi = *(const f32x4*)(p + 4);
                a0[0] = (short)f2bf(lo[0]); a0[1] = (short)f2bf(lo[1]);
                a0[2] = (short)f2bf(lo[2]); a0[3] = (short)f2bf(lo[3]);
                a0[4] = (short)f2bf(hi[0]); a0[5] = (short)f2bf(hi[1]);
                a0[6] = (short)f2bf(hi[2]); a0[7] = (short)f2bf(hi[3]);
            }
            if (r1 < M) {
                const float* p = A + (size_t)r1 * 128 + k0;
                f32x4 lo = *(const f32x4*)p, hi = *(const f32x4*)(p + 4);
                a1[0] = (short)f2bf(lo[0]); a1[1] = (short)f2bf(lo[1]);
                a1[2] = (short)f2bf(lo[2]); a1[3] = (short)f2bf(lo[3]);
                a1[4] = (short)f2bf(hi[0]); a1[5] = (short)f2bf(hi[1]);
                a1[6] = (short)f2bf(hi[2]); a1[7] = (short)f2bf(hi[3]);
            }
        }
#pragma unroll
        for (int nt = 0; nt < NT; nt++) {
            bf16x8 b = *(const bf16x8*)(Bs + (nt * 4 + ks) * 512 + fb);
            acc[0][nt] = __builtin_amdgcn_mfma_f32_16x16x32_bf16(a0, b, acc[0][nt], 0, 0, 0);
            acc[1][nt] = __builtin_amdgcn_mfma_f32_16x16x32_bf16(a1, b, acc[1][nt], 0, 0, 0);
        }
    }

    // ---- epilogue: scale by dinv, store bf16 ----
#pragma unroll
    for (int lt = 0; lt < 2; lt++) {
#pragma unroll
        for (int r = 0; r < 4; r++) {
            int row = row0 + w * 32 + lt * 16 + q * 4 + r;
            if (row < M) {
                float s = dinv[row];
#pragma unroll
                for (int nt = 0; nt < NT; nt++)
                    out[(size_t)row * BN + nt * 16 + m] = f2bf(acc[lt][nt][r] * s);
            }
        }
    }
}

// ---------------- gather aggregation + fused epilogue (round-0 proven) -----
// out[i] = maybe_relu( dinv[i] * ( hs[i] + sum_{e in row i} hs[csr[e]] ) + b )
// Lane owns 8 channels (uint4 = 16 B of bf16). LPN = C/8 lanes per node.
template <int C, bool RELU, bool OUTBF>
__global__ __launch_bounds__(256) void agg_kernel(
    const int* __restrict__ csr, const unsigned* __restrict__ row,
    const unsigned short* __restrict__ hsb, const float* __restrict__ dinv,
    const float* __restrict__ bias, void* __restrict__ outv, int N) {
    constexpr int LPN = C / 8;  // lanes per node (16 or 8)
    const int tid = blockIdx.x * 256 + threadIdx.x;
    const int i = tid / LPN;
    const int l = tid % LPN;
    if (i >= N) return;

    const int co = 8 * l;
    float s0 = 0.f, s1 = 0.f, s2 = 0.f, s3 = 0.f,
          s4 = 0.f, s5 = 0.f, s6 = 0.f, s7 = 0.f;
    {
        uint4 u = *(const uint4*)(hsb + (size_t)i * C + co);   // self
        s0 += __uint_as_float(u.x << 16); s1 += __uint_as_float(u.x & 0xffff0000u);
        s2 += __uint_as_float(u.y << 16); s3 += __uint_as_float(u.y & 0xffff0000u);
        s4 += __uint_as_float(u.z << 16); s5 += __uint_as_float(u.z & 0xffff0000u);
        s6 += __uint_as_float(u.w << 16); s7 += __uint_as_float(u.w & 0xffff0000u);
    }

    const int rs = (int)row[i], re = (int)row[i + 1];
    for (int e0 = rs; e0 < re; e0 += LPN) {
        int idx = (e0 + l < re) ? csr[e0 + l] : 0;
        const int cnt = min(LPN, re - e0);
#pragma unroll 4
        for (int j = 0; j < cnt; j++) {
            int s = __shfl(idx, j, LPN);
            uint4 u = *(const uint4*)(hsb + (size_t)s * C + co);
            s0 += __uint_as_float(u.x << 16); s1 += __uint_as_float(u.x & 0xffff0000u);
            s2 += __uint_as_float(u.y << 16); s3 += __uint_as_float(u.y & 0xffff0000u);
            s4 += __uint_as_float(u.z << 16); s5 += __uint_as_float(u.z & 0xffff0000u);
            s6 += __uint_as_float(u.w << 16); s7 += __uint_as_float(u.w & 0xffff0000u);
        }
    }

    const float sc = dinv[i];
    const float4 ba = *(const float4*)(bias + co);
    const float4 bb = *(const float4*)(bias + co + 4);
    float o0 = s0 * sc + ba.x, o1 = s1 * sc + ba.y;
    float o2 = s2 * sc + ba.z, o3 = s3 * sc + ba.w;
    float o4 = s4 * sc + bb.x, o5 = s5 * sc + bb.y;
    float o6 = s6 * sc + bb.z, o7 = s7 * sc + bb.w;
    if (RELU) {
        o0 = fmaxf(o0, 0.f); o1 = fmaxf(o1, 0.f); o2 = fmaxf(o2, 0.f);
        o3 = fmaxf(o3, 0.f); o4 = fmaxf(o4, 0.f); o5 = fmaxf(o5, 0.f);
        o6 = fmaxf(o6, 0.f); o7 = fmaxf(o7, 0.f);
    }
    if (OUTBF) {
        uint4 u;
        u.x = (unsigned)f2bf(o0) | ((unsigned)f2bf(o1) << 16);
        u.y = (unsigned)f2bf(o2) | ((unsigned)f2bf(o3) << 16);
        u.z = (unsigned)f2bf(o4) | ((unsigned)f2bf(o5) << 16);
        u.w = (unsigned)f2bf(o6) | ((unsigned)f2bf(o7) << 16);
        *(uint4*)((unsigned short*)outv + (size_t)i * C + co) = u;
    } else {
        float4 a = make_float4(o0, o1, o2, o3);
        float4 b = make_float4(o4, o5, o6, o7);
        *(float4*)((float*)outv + (size_t)i * C + co) = a;
        *(float4*)((float*)outv + (size_t)i * C + co + 4) = b;
    }
}

// ---------------- launch ----------------
extern "C" void kernel_launch(void* const* d_in, const int* in_sizes, int n_in,
                              void* d_out, int out_size, void* d_ws,
                              size_t ws_size, hipStream_t stream) {
    const float* x  = (const float*)d_in[0];
    const float* W1 = (const float*)d_in[1];
    const float* b1 = (const float*)d_in[2];
    const float* W2 = (const float*)d_in[3];
    const float* b2 = (const float*)d_in[4];
    const unsigned* ew = (const unsigned*)d_in[5];
    const int E = in_sizes[5] / 2;        // 1,600,000
    const int N = in_sizes[0] / 128;      // 100,000
    const int NB = (N + 1023) >> 10;
    const int nbuck = (N + BWIDTH - 1) >> BSHIFT;   // 782

    char* ws = (char*)d_ws;
    unsigned* flag = (unsigned*)(ws + OFF_FLAG);
    unsigned* deg  = (unsigned*)(ws + OFF_DEG);
    unsigned* row  = (unsigned*)(ws + OFF_ROW);
    unsigned* bsum = (unsigned*)(ws + OFF_BSUM);
    unsigned* ccnt = (unsigned*)(ws + OFF_CCNT);
    unsigned* coff = (unsigned*)(ws + OFF_COFF);
    float* dinv    = (float*)(ws + OFF_DINV);
    int* csr       = (int*)(ws + OFF_CSR);
    unsigned short* hs1  = (unsigned short*)(ws + OFF_HS1);
    unsigned short* out1 = (unsigned short*)(ws + OFF_OUT1);
    unsigned short* hs2  = (unsigned short*)(ws + OFF_HS2);
    unsigned* h2   = (unsigned*)(ws + OFF_H2);
    unsigned short* w1s  = (unsigned short*)(ws + OFF_W1S);
    unsigned short* w2s  = (unsigned short*)(ws + OFF_W2S);
    unsigned* part = (unsigned*)(ws + OFF_HS1);  // dead before gemm1 writes hs1

    hipMemsetAsync(flag, 0, 4, stream);

    // ---- W pre-swizzle (independent of everything else) ----
    wprep_kernel<<<2, 256, 0, stream>>>(W1, W2, w1s, w2s);

    // ---- CSR build (round-0 bucketed chain) ----
    detect_kernel<<<16, 256, 0, stream>>>(ew, flag, ccnt, nbuck);
    coarse_hist_kernel<<<NPART, 1024, 0, stream>>>(ew, flag, ccnt, h2, E, nbuck);
    coarse_scan_kernel<<<1, 1024, 0, stream>>>(ccnt, coff, nbuck);
    off2d_kernel<<<nbuck, NPART, 0, stream>>>(h2, coff);
    partition_kernel<<<NPART, 1024, 0, stream>>>(ew, flag, h2, part, E, nbuck);
    bucket_csr_kernel<<<nbuck, 256, 0, stream>>>(part, coff, deg, csr, N);
    scan1_kernel<<<NB, 1024, 0, stream>>>(deg, row, bsum, N);
    scan2_kernel<<<1, 1024, 0, stream>>>(bsum, NB);
    scan3_kernel<<<(N + 255) / 256, 256, 0, stream>>>(row, bsum, deg, dinv, N);

    // ---- layer 1 (C=128) ----
    gemm_mfma<128, false><<<(N + 127) / 128, 256, 0, stream>>>(x, w1s, dinv, hs1, N);
    agg_kernel<128, true, true><<<(N * 16 + 255) / 256, 256, 0, stream>>>(
        csr, row, hs1, dinv, b1, out1, N);

    // ---- layer 2 (C=64) ----
    gemm_mfma<64, true><<<(N + 127) / 128, 256, 0, stream>>>(out1, w2s, dinv, hs2, N);
    agg_kernel<64, false, false><<<(N * 8 + 255) / 256, 256, 0, stream>>>(
        csr, row, hs2, dinv, b2, d_out, N);
}

// Round 6
// 278.944 us; speedup vs baseline: 1.5929x; 1.0958x over previous
//
#include <hip/hip_runtime.h>

// ---------------- problem constants ----------------
// x:[N,128] W1:[128,128] b1:[128] W2:[128,64] b2:[64] edge_index:[2,E]
// out:[N,64] fp32. Intermediates bf16; GEMMs use bf16 MFMA (fp32 accum).
// CSR build: bucketed-partition chain (random writes stay line-local; round-4
// measured: naive atomic scatter = 105 MB write-allocate, 130 us).
// Dispatch-minimized: row/dinv fused into bucket_csr (scan1/2/3 deleted),
// edge-dtype flag self-detected per block (detect kernel deleted),
// coarse_scan+off2d merged, wprep merged into hist dispatch. 10 GPU ops.

static constexpr int BSHIFT = 7;          // 128 node ids per coarse bucket
static constexpr int BWIDTH = 1 << BSHIFT;
static constexpr int MAXBUCK = 2048;      // supports N <= 262144 (pack needs N < 2^20)
static constexpr int NPART = 256;         // partition/hist grid size

// ---------------- workspace layout (bytes) ----------------
static constexpr size_t OFF_ROW  = 458752;    // u32[N+1]
static constexpr size_t OFF_CCNT = 925696;    // u32[MAXBUCK+1]
static constexpr size_t OFF_COFF = 937984;    // u32[MAXBUCK+1]
static constexpr size_t OFF_DINV = 962560;    // f32[N]
static constexpr size_t OFF_CSR  = 1376256;   // i32[E]            (6.4 MB)
static constexpr size_t OFF_HS1  = 8388608;   // bf16[N*128] 25.6 MB; aliases part u32[E]
static constexpr size_t OFF_OUT1 = 35651584;  // bf16[N*128] 25.6 MB
static constexpr size_t OFF_HS2  = 62914560;  // bf16[N*64]  12.8 MB (ends 75714560)
static constexpr size_t OFF_H2   = 75714560;  // u32[MAXBUCK*NPART] (2 MB region)
static constexpr size_t OFF_W1S  = 77811712;  // bf16[128*128] swizzled (32 KB)
static constexpr size_t OFF_W2S  = 77844480;  // bf16[128*64]  swizzled (16 KB)

// ---------------- bf16 helpers ----------------
__device__ __forceinline__ unsigned short f2bf(float f) {  // RNE
    unsigned u = __float_as_uint(f);
    u += 0x7fffu + ((u >> 16) & 1u);
    return (unsigned short)(u >> 16);
}

typedef __attribute__((ext_vector_type(8))) short bf16x8;
typedef __attribute__((ext_vector_type(4))) float f32x4;

// ---------------- edge dtype self-detection ----------------
// int64 [2,E]: odd u32 words of the first 16 src entries are high words == 0.
// int32 [2,E]: those words are src node ids; P(16 random ids all zero) ~ 0.
__device__ __forceinline__ unsigned detect_flag(const unsigned* __restrict__ w) {
    unsigned fl = 0;
#pragma unroll
    for (int k = 1; k < 32; k += 2) fl |= w[k];   // 16 wave-uniform loads
    return fl;
}

__device__ __forceinline__ int edge_dst(const unsigned* w, unsigned flag,
                                        int e, int E) {
    return flag ? (int)w[E + e] : (int)w[2 * E + 2 * e];
}
__device__ __forceinline__ int edge_src(const unsigned* w, unsigned flag,
                                        int e, int E) {
    return flag ? (int)w[e] : (int)w[2 * e];
}

// ---------------- pass A: coarse histogram + merged W pre-swizzle ----------
// Blocks [0,NPART): per-block bucket histogram of dst>>7 into h2 + ccnt.
// Blocks NPART, NPART+1: swizzle W1/W2 fp32 -> bf16 frag tables.
// frag layout (m89-verified): element (k,n) ->
//   ((((n>>4)*4 + (k>>5))*16 + (n&15))*4 + ((k>>3)&3))*8 + (k&7)
__global__ __launch_bounds__(1024) void hist_wprep_kernel(
    const unsigned* __restrict__ w, unsigned* __restrict__ ccnt,
    unsigned* __restrict__ h2, int E, int nbuck,
    const float* __restrict__ W1, const float* __restrict__ W2,
    unsigned short* __restrict__ O1, unsigned short* __restrict__ O2) {
    if (blockIdx.x >= NPART) {   // ---- W prep ----
        const int which = blockIdx.x - NPART;
        const float* W = which ? W2 : W1;
        unsigned short* O = which ? O2 : O1;
        const int BN = which ? 64 : 128;
        const int total = 128 * BN / 4;
        for (int g = threadIdx.x; g < total; g += 1024) {
            int n = g % BN, k0 = (g / BN) * 4;
            ushort4 u;
            u.x = f2bf(W[(size_t)(k0 + 0) * BN + n]);
            u.y = f2bf(W[(size_t)(k0 + 1) * BN + n]);
            u.z = f2bf(W[(size_t)(k0 + 2) * BN + n]);
            u.w = f2bf(W[(size_t)(k0 + 3) * BN + n]);
            int off = ((((n >> 4) * 4 + (k0 >> 5)) * 16 + (n & 15)) * 4 +
                       ((k0 >> 3) & 3)) * 8 + (k0 & 4);
            *(ushort4*)(O + off) = u;
        }
        return;
    }
    __shared__ unsigned hist[MAXBUCK];
    for (int i = threadIdx.x; i < nbuck; i += 1024) hist[i] = 0;
    __syncthreads();
    const unsigned f = detect_flag(w);
    const int per = (E + NPART - 1) / NPART;
    const int e0 = blockIdx.x * per, e1 = min(E, e0 + per);
    for (int e = e0 + (int)threadIdx.x; e < e1; e += 1024)
        atomicAdd(&hist[edge_dst(w, f, e, E) >> BSHIFT], 1u);
    __syncthreads();
    for (int i = threadIdx.x; i < nbuck; i += 1024) {
        unsigned h = hist[i];
        h2[(size_t)i * NPART + blockIdx.x] = h;
        if (h) atomicAdd(&ccnt[i], h);
    }
}

// ---------------- merged coarse scan + off2d --------------------------------
// Block b: coff[b] = sum_{i<b} ccnt[i]; then per-block cursor
// h2[b][t] = coff[b] + excl_scan_t(h2[b][:]).
__global__ __launch_bounds__(NPART) void scanoff_kernel(
    const unsigned* __restrict__ ccnt, unsigned* __restrict__ coff,
    unsigned* __restrict__ h2, int nbuck) {
    __shared__ unsigned red[NPART];
    __shared__ unsigned sh[NPART];
    const int b = blockIdx.x, t = threadIdx.x;
    unsigned p = 0;
    for (int i = t; i < b; i += NPART) p += ccnt[i];
    red[t] = p;
    __syncthreads();
#pragma unroll
    for (int off = NPART / 2; off > 0; off >>= 1) {
        if (t < off) red[t] += red[t + off];
        __syncthreads();
    }
    const unsigned coffb = red[0];
    if (t == 0) {
        coff[b] = coffb;
        if (b == nbuck - 1) coff[nbuck] = coffb + ccnt[b];
    }
    unsigned v = h2[(size_t)b * NPART + t];
    sh[t] = v;
    __syncthreads();
#pragma unroll
    for (int off = 1; off < NPART; off <<= 1) {
        unsigned a = (t >= off) ? sh[t - off] : 0u;
        __syncthreads();
        sh[t] += a;
        __syncthreads();
    }
    h2[(size_t)b * NPART + t] = coffb + sh[t] - v;   // exclusive + base
}

// ---------------- pass B: partition (packed 4 B entries) ----------------
// part entry = src | (dst&127)<<20  (valid: N < 2^20)
__global__ __launch_bounds__(1024) void partition_kernel(
    const unsigned* __restrict__ w, const unsigned* __restrict__ h2,
    unsigned* __restrict__ part, int E, int nbuck) {
    __shared__ unsigned lcur[MAXBUCK];
    for (int i = threadIdx.x; i < nbuck; i += 1024)
        lcur[i] = h2[(size_t)i * NPART + blockIdx.x];
    __syncthreads();
    const unsigned f = detect_flag(w);
    const int per = (E + NPART - 1) / NPART;
    const int e0 = blockIdx.x * per, e1 = min(E, e0 + per);
    for (int e = e0 + (int)threadIdx.x; e < e1; e += 1024) {
        int d = edge_dst(w, f, e, E);
        int s = edge_src(w, f, e, E);
        unsigned pos = atomicAdd(&lcur[d >> BSHIFT], 1u);
        part[pos] = (unsigned)s | ((unsigned)(d & (BWIDTH - 1)) << 20);
    }
}

// ---------------- pass C: per-bucket CSR + row + dinv (scans fused) --------
// cur[t] init == row[base+t]; cnt[t] == deg[base+t]  ->  write row/dinv here.
__global__ __launch_bounds__(256) void bucket_csr_kernel(
    const unsigned* __restrict__ part, const unsigned* __restrict__ coff,
    unsigned* __restrict__ row, float* __restrict__ dinv,
    int* __restrict__ csr, int N) {
    __shared__ unsigned cnt[BWIDTH];
    __shared__ unsigned sc[BWIDTH];
    __shared__ unsigned cur[BWIDTH];
    const int b = blockIdx.x, base = b << BSHIFT, t = threadIdx.x;
    if (t < BWIDTH) cnt[t] = 0;
    __syncthreads();
    const int e0 = (int)coff[b], e1 = (int)coff[b + 1];
    for (int e = e0 + t; e < e1; e += 256)
        atomicAdd(&cnt[part[e] >> 20], 1u);
    __syncthreads();
    if (t < BWIDTH) sc[t] = cnt[t];
    __syncthreads();
#pragma unroll
    for (int off = 1; off < BWIDTH; off <<= 1) {
        unsigned a = (t < BWIDTH && t >= off) ? sc[t - off] : 0u;
        __syncthreads();
        if (t < BWIDTH) sc[t] += a;
        __syncthreads();
    }
    if (t < BWIDTH) {
        unsigned r = (unsigned)e0 + sc[t] - cnt[t];   // row[base+t]
        cur[t] = r;
        if (base + t < N) {
            row[base + t] = r;
            dinv[base + t] = rsqrtf((float)cnt[t] + 1.0f);
        }
    }
    if (t == 0 && b == (int)gridDim.x - 1) row[N] = (unsigned)e1;  // == E
    __syncthreads();
    for (int e = e0 + t; e < e1; e += 256) {
        unsigned pk = part[e];
        unsigned p = atomicAdd(&cur[pk >> 20], 1u);
        csr[p] = (int)(pk & 0xFFFFFu);
    }
}

// ---------------- LDS-free MFMA GEMM: out_bf16 = (A @ B) * dinv[row] -------
// 128xBN rows per block, K=128, 16x16x32 bf16 MFMA, 4 waves x 2 m-tiles.
// A frags direct from global; B frags from pre-swizzled L1-resident table.
template <int BN, bool ABF16>
__global__ __launch_bounds__(256) void gemm_mfma(
    const void* __restrict__ Av, const unsigned short* __restrict__ Bs,
    const float* __restrict__ dinv, unsigned short* __restrict__ out, int M) {
    constexpr int NT = BN / 16;
    const int t = threadIdx.x;
    const int row0 = blockIdx.x * 128;
    const int w = t >> 6, lane = t & 63;
    const int m = lane & 15, q = lane >> 4;
    const int fb = (m * 4 + q) * 8;

    const int r0 = row0 + (2 * w) * 16 + m;       // m-tile 2w
    const int r1 = r0 + 16;                        // m-tile 2w+1

    f32x4 acc[2][NT];
#pragma unroll
    for (int lt = 0; lt < 2; lt++)
#pragma unroll
        for (int nt = 0; nt < NT; nt++) acc[lt][nt] = (f32x4){0.f, 0.f, 0.f, 0.f};

#pragma unroll
    for (int ks = 0; ks < 4; ks++) {
        const int k0 = ks * 32 + q * 8;
        bf16x8 a0 = (bf16x8){0, 0, 0, 0, 0, 0, 0, 0};
        bf16x8 a1 = (bf16x8){0, 0, 0, 0, 0, 0, 0, 0};
        if (ABF16) {
            const unsigned short* A = (const unsigned short*)Av;
            if (r0 < M) a0 = *(const bf16x8*)(A + (size_t)r0 * 128 + k0);
            if (r1 < M) a1 = *(const bf16x8*)(A + (size_t)r1 * 128 + k0);
        } else {
            const float* A = (const float*)Av;
            if (r0 < M) {
                const float* p = A + (size_t)r0 * 128 + k0;
                f32x4 lo = *(const f32x4*)p, hi = *(const f32x4*)(p + 4);
                a0[0] = (short)f2bf(lo[0]); a0[1] = (short)f2bf(lo[1]);
                a0[2] = (short)f2bf(lo[2]); a0[3] = (short)f2bf(lo[3]);
                a0[4] = (short)f2bf(hi[0]); a0[5] = (short)f2bf(hi[1]);
                a0[6] = (short)f2bf(hi[2]); a0[7] = (short)f2bf(hi[3]);
            }
            if (r1 < M) {
                const float* p = A + (size_t)r1 * 128 + k0;
                f32x4 lo = *(const f32x4*)p, hi = *(const f32x4*)(p + 4);
                a1[0] = (short)f2bf(lo[0]); a1[1] = (short)f2bf(lo[1]);
                a1[2] = (short)f2bf(lo[2]); a1[3] = (short)f2bf(lo[3]);
                a1[4] = (short)f2bf(hi[0]); a1[5] = (short)f2bf(hi[1]);
                a1[6] = (short)f2bf(hi[2]); a1[7] = (short)f2bf(hi[3]);
            }
        }
#pragma unroll
        for (int nt = 0; nt < NT; nt++) {
            bf16x8 b = *(const bf16x8*)(Bs + (nt * 4 + ks) * 512 + fb);
            acc[0][nt] = __builtin_amdgcn_mfma_f32_16x16x32_bf16(a0, b, acc[0][nt], 0, 0, 0);
            acc[1][nt] = __builtin_amdgcn_mfma_f32_16x16x32_bf16(a1, b, acc[1][nt], 0, 0, 0);
        }
    }

    // ---- epilogue: scale by dinv, store bf16 ----
#pragma unroll
    for (int lt = 0; lt < 2; lt++) {
#pragma unroll
        for (int r = 0; r < 4; r++) {
            int row = row0 + w * 32 + lt * 16 + q * 4 + r;
            if (row < M) {
                float s = dinv[row];
#pragma unroll
                for (int nt = 0; nt < NT; nt++)
                    out[(size_t)row * BN + nt * 16 + m] = f2bf(acc[lt][nt][r] * s);
            }
        }
    }
}

// ---------------- gather aggregation + fused epilogue (round-0 proven) -----
// out[i] = maybe_relu( dinv[i] * ( hs[i] + sum_{e in row i} hs[csr[e]] ) + b )
// Lane owns 8 channels (uint4 = 16 B of bf16). LPN = C/8 lanes per node.
template <int C, bool RELU, bool OUTBF>
__global__ __launch_bounds__(256) void agg_kernel(
    const int* __restrict__ csr, const unsigned* __restrict__ row,
    const unsigned short* __restrict__ hsb, const float* __restrict__ dinv,
    const float* __restrict__ bias, void* __restrict__ outv, int N) {
    constexpr int LPN = C / 8;  // lanes per node (16 or 8)
    const int tid = blockIdx.x * 256 + threadIdx.x;
    const int i = tid / LPN;
    const int l = tid % LPN;
    if (i >= N) return;

    const int co = 8 * l;
    float s0 = 0.f, s1 = 0.f, s2 = 0.f, s3 = 0.f,
          s4 = 0.f, s5 = 0.f, s6 = 0.f, s7 = 0.f;
    {
        uint4 u = *(const uint4*)(hsb + (size_t)i * C + co);   // self
        s0 += __uint_as_float(u.x << 16); s1 += __uint_as_float(u.x & 0xffff0000u);
        s2 += __uint_as_float(u.y << 16); s3 += __uint_as_float(u.y & 0xffff0000u);
        s4 += __uint_as_float(u.z << 16); s5 += __uint_as_float(u.z & 0xffff0000u);
        s6 += __uint_as_float(u.w << 16); s7 += __uint_as_float(u.w & 0xffff0000u);
    }

    const int rs = (int)row[i], re = (int)row[i + 1];
    for (int e0 = rs; e0 < re; e0 += LPN) {
        int idx = (e0 + l < re) ? csr[e0 + l] : 0;
        const int cnt = min(LPN, re - e0);
#pragma unroll 4
        for (int j = 0; j < cnt; j++) {
            int s = __shfl(idx, j, LPN);
            uint4 u = *(const uint4*)(hsb + (size_t)s * C + co);
            s0 += __uint_as_float(u.x << 16); s1 += __uint_as_float(u.x & 0xffff0000u);
            s2 += __uint_as_float(u.y << 16); s3 += __uint_as_float(u.y & 0xffff0000u);
            s4 += __uint_as_float(u.z << 16); s5 += __uint_as_float(u.z & 0xffff0000u);
            s6 += __uint_as_float(u.w << 16); s7 += __uint_as_float(u.w & 0xffff0000u);
        }
    }

    const float sc = dinv[i];
    const float4 ba = *(const float4*)(bias + co);
    const float4 bb = *(const float4*)(bias + co + 4);
    float o0 = s0 * sc + ba.x, o1 = s1 * sc + ba.y;
    float o2 = s2 * sc + ba.z, o3 = s3 * sc + ba.w;
    float o4 = s4 * sc + bb.x, o5 = s5 * sc + bb.y;
    float o6 = s6 * sc + bb.z, o7 = s7 * sc + bb.w;
    if (RELU) {
        o0 = fmaxf(o0, 0.f); o1 = fmaxf(o1, 0.f); o2 = fmaxf(o2, 0.f);
        o3 = fmaxf(o3, 0.f); o4 = fmaxf(o4, 0.f); o5 = fmaxf(o5, 0.f);
        o6 = fmaxf(o6, 0.f); o7 = fmaxf(o7, 0.f);
    }
    if (OUTBF) {
        uint4 u;
        u.x = (unsigned)f2bf(o0) | ((unsigned)f2bf(o1) << 16);
        u.y = (unsigned)f2bf(o2) | ((unsigned)f2bf(o3) << 16);
        u.z = (unsigned)f2bf(o4) | ((unsigned)f2bf(o5) << 16);
        u.w = (unsigned)f2bf(o6) | ((unsigned)f2bf(o7) << 16);
        *(uint4*)((unsigned short*)outv + (size_t)i * C + co) = u;
    } else {
        float4 a = make_float4(o0, o1, o2, o3);
        float4 b = make_float4(o4, o5, o6, o7);
        *(float4*)((float*)outv + (size_t)i * C + co) = a;
        *(float4*)((float*)outv + (size_t)i * C + co + 4) = b;
    }
}

// ---------------- launch ----------------
extern "C" void kernel_launch(void* const* d_in, const int* in_sizes, int n_in,
                              void* d_out, int out_size, void* d_ws,
                              size_t ws_size, hipStream_t stream) {
    const float* x  = (const float*)d_in[0];
    const float* W1 = (const float*)d_in[1];
    const float* b1 = (const float*)d_in[2];
    const float* W2 = (const float*)d_in[3];
    const float* b2 = (const float*)d_in[4];
    const unsigned* ew = (const unsigned*)d_in[5];
    const int E = in_sizes[5] / 2;        // 1,600,000
    const int N = in_sizes[0] / 128;      // 100,000
    const int nbuck = (N + BWIDTH - 1) >> BSHIFT;   // 782

    char* ws = (char*)d_ws;
    unsigned* row  = (unsigned*)(ws + OFF_ROW);
    unsigned* ccnt = (unsigned*)(ws + OFF_CCNT);
    unsigned* coff = (unsigned*)(ws + OFF_COFF);
    float* dinv    = (float*)(ws + OFF_DINV);
    int* csr       = (int*)(ws + OFF_CSR);
    unsigned short* hs1  = (unsigned short*)(ws + OFF_HS1);
    unsigned short* out1 = (unsigned short*)(ws + OFF_OUT1);
    unsigned short* hs2  = (unsigned short*)(ws + OFF_HS2);
    unsigned* h2   = (unsigned*)(ws + OFF_H2);
    unsigned short* w1s  = (unsigned short*)(ws + OFF_W1S);
    unsigned short* w2s  = (unsigned short*)(ws + OFF_W2S);
    unsigned* part = (unsigned*)(ws + OFF_HS1);  // dead before gemm1 writes hs1

    hipMemsetAsync(ccnt, 0, (size_t)(nbuck + 1) * 4, stream);

    // ---- CSR build (4 kernels) + W prep merged ----
    hist_wprep_kernel<<<NPART + 2, 1024, 0, stream>>>(ew, ccnt, h2, E, nbuck,
                                                      W1, W2, w1s, w2s);
    scanoff_kernel<<<nbuck, NPART, 0, stream>>>(ccnt, coff, h2, nbuck);
    partition_kernel<<<NPART, 1024, 0, stream>>>(ew, h2, part, E, nbuck);
    bucket_csr_kernel<<<nbuck, 256, 0, stream>>>(part, coff, row, dinv, csr, N);

    // ---- layer 1 (C=128) ----
    gemm_mfma<128, false><<<(N + 127) / 128, 256, 0, stream>>>(x, w1s, dinv, hs1, N);
    agg_kernel<128, true, true><<<(N * 16 + 255) / 256, 256, 0, stream>>>(
        csr, row, hs1, dinv, b1, out1, N);

    // ---- layer 2 (C=64) ----
    gemm_mfma<64, true><<<(N + 127) / 128, 256, 0, stream>>>(out1, w2s, dinv, hs2, N);
    agg_kernel<64, false, false><<<(N * 8 + 255) / 256, 256, 0, stream>>>(
        csr, row, hs2, dinv, b2, d_out, N);
}